// Round 3
// baseline (574.174 us; speedup 1.0000x reference)
//
#include <hip/hip_runtime.h>
#include <math.h>

#define NN 100000
#define NE 3200000
#define CF 512

// ---- ws layout (bytes) ----
// s    : float[NN] @ 0        (zeroed per launch via hipMemsetAsync)
// deg  : u32[NN]   @ 400000   (zeroed per launch via same memset)
// h    : float[NN] @ 800000
// g    : float[NN] @ 1200000
// dinv : float[NN] @ 1600000
#define OFF_S    0
#define OFF_DEG  400000
#define OFF_H    800000
#define OFF_G    1200000
#define OFF_DINV 1600000

// Per-wave int64-layout self-detect (high words of int64 edge values are 0;
// for int32 layout those words are edge values, ~never all zero).
__device__ __forceinline__ bool detect_f64(const int* e32) {
    unsigned v = ((const unsigned*)e32)[2 * (threadIdx.x & 63) + 1];
    return __ballot(v != 0u) == 0ULL;
}

// Load 4 consecutive cols starting at edge e (e % 4 == 0)
__device__ __forceinline__ int4 load_col4(const int* e32, bool f64, int e) {
    if (f64) {
        const int4* q = (const int4*)(e32 + 2 * (NE + e));  // 2 int64 per int4
        int4 a = q[0], b = q[1];
        return make_int4(a.x, a.z, b.x, b.z);
    }
    return *(const int4*)(e32 + NE + e);
}
// Load 4 consecutive rows starting at edge e (e % 4 == 0)
__device__ __forceinline__ int4 load_row4(const int* e32, bool f64, int e) {
    if (f64) {
        const int4* q = (const int4*)(e32 + 2 * e);
        int4 a = q[0], b = q[1];
        return make_int4(a.x, a.z, b.x, b.z);
    }
    return *(const int4*)(e32 + e);
}

// ---------------------------------------------------------------------------
// K1 (block-specialized):
//   blocks [0, EDGE_BLKS)         : deg[col]++ via global atomics (edge read 1x)
//   blocks [EDGE_BLKS, +H_BLKS)   : h = x @ W^T  (wave-per-node, 2-node ILP)
// Independent phases share the GPU: edge pass (latency/atomic-bound) hides
// under the x-stream (BW-bound, ~33 us floor).
// ---------------------------------------------------------------------------
#define EDGE_BLKS 512
#define H_BLKS    1536
#define K1_BLKS   (EDGE_BLKS + H_BLKS)   // 2048 blocks x 256 thr = 8 blk/CU

__global__ __launch_bounds__(256) void deg_h_kernel(const int* __restrict__ e32,
                                                    const float* __restrict__ x,
                                                    const float* __restrict__ W,
                                                    unsigned* __restrict__ deg,
                                                    float* __restrict__ h) {
    int blk = blockIdx.x;
    if (blk < EDGE_BLKS) {
        bool f64 = detect_f64(e32);
        int gid = blk * 256 + threadIdx.x;
        const int STRIDE = EDGE_BLKS * 256 * 4;   // 524288 edges per sweep
        for (int e = gid * 4; e < NE; e += STRIDE) {
            int4 c = load_col4(e32, f64, e);
            atomicAdd(&deg[c.x], 1u);
            atomicAdd(&deg[c.y], 1u);
            atomicAdd(&deg[c.z], 1u);
            atomicAdd(&deg[c.w], 1u);
        }
    } else {
        int wave = (blk - EDGE_BLKS) * 4 + (threadIdx.x >> 6);
        int lane = threadIdx.x & 63;
        const float4* Wr = (const float4*)W;
        float4 w0 = Wr[lane], w1 = Wr[lane + 64];   // W invariant, in regs
        const int NWAVES = H_BLKS * 4;              // 6144 waves
        for (int i = wave * 2; i < NN; i += NWAVES * 2) {
            int i1 = i + 1;
            float s0 = 0.f, s1 = 0.f;
            {
                const float4* xr = (const float4*)(x + (size_t)i * CF);
                float4 a = xr[lane], bq = xr[lane + 64];
                s0 = a.x * w0.x + a.y * w0.y + a.z * w0.z + a.w * w0.w
                   + bq.x * w1.x + bq.y * w1.y + bq.z * w1.z + bq.w * w1.w;
            }
            if (i1 < NN) {
                const float4* xr = (const float4*)(x + (size_t)i1 * CF);
                float4 a = xr[lane], bq = xr[lane + 64];
                s1 = a.x * w0.x + a.y * w0.y + a.z * w0.z + a.w * w0.w
                   + bq.x * w1.x + bq.y * w1.y + bq.z * w1.z + bq.w * w1.w;
            }
#pragma unroll
            for (int off = 32; off >= 1; off >>= 1) {
                s0 += __shfl_down(s0, off, 64);
                s1 += __shfl_down(s1, off, 64);
            }
            if (lane == 0) {
                h[i] = s0;
                if (i1 < NN) h[i1] = s1;
            }
        }
    }
}

// K2: dinv[i] = rsqrt(1 + deg[i]);  g[i] = h[i] * dinv[i]
__global__ __launch_bounds__(256) void dinv_g_kernel(const unsigned* __restrict__ deg,
                                                     const float* __restrict__ h,
                                                     float* __restrict__ dinv,
                                                     float* __restrict__ g) {
    int i = blockIdx.x * 256 + threadIdx.x;
    if (i >= NN) return;
    float di = rsqrtf((float)(1u + deg[i]));
    dinv[i] = di;
    g[i] = h[i] * di;
}

// K3: s[col] += g[row] via global f32 atomics (edge read 1x, s fits L2)
#define SC_BLKS 1024
__global__ __launch_bounds__(256) void scatter_kernel(const int* __restrict__ e32,
                                                      const float* __restrict__ g,
                                                      float* __restrict__ s) {
    bool f64 = detect_f64(e32);
    int gid = blockIdx.x * 256 + threadIdx.x;
    const int STRIDE = SC_BLKS * 256 * 4;   // 1048576 edges per sweep
    for (int e = gid * 4; e < NE; e += STRIDE) {
        int4 c = load_col4(e32, f64, e);
        int4 r = load_row4(e32, f64, e);
        float g0 = g[r.x], g1 = g[r.y], g2 = g[r.z], g3 = g[r.w];
        atomicAdd(&s[c.x], g0);
        atomicAdd(&s[c.y], g1);
        atomicAdd(&s[c.z], g2);
        atomicAdd(&s[c.w], g3);
    }
}

// K4: out[i] = sigmoid(dinv[i] * (s[i] + g[i]) + b)
__global__ __launch_bounds__(256) void final_kernel(const float* __restrict__ s,
                                                    const float* __restrict__ g,
                                                    const float* __restrict__ dinv,
                                                    const float* __restrict__ b,
                                                    float* __restrict__ out) {
    int i = blockIdx.x * 256 + threadIdx.x;
    if (i >= NN) return;
    float v = dinv[i] * (s[i] + g[i]) + b[0];
    out[i] = 1.f / (1.f + expf(-v));
}

extern "C" void kernel_launch(void* const* d_in, const int* in_sizes, int n_in,
                              void* d_out, int out_size, void* d_ws, size_t ws_size,
                              hipStream_t stream) {
    const float* x = (const float*)d_in[0];
    const int* eidx = (const int*)d_in[1];
    const float* W = (const float*)d_in[2];
    const float* b = (const float*)d_in[3];
    float* out = (float*)d_out;

    char* ws = (char*)d_ws;
    float* s = (float*)(ws + OFF_S);
    unsigned* deg = (unsigned*)(ws + OFF_DEG);
    float* h = (float*)(ws + OFF_H);
    float* g = (float*)(ws + OFF_G);
    float* dinv = (float*)(ws + OFF_DINV);

    // zero s + deg (contiguous 800 KB); ws is re-poisoned between iterations
    hipMemsetAsync(ws, 0, 800000, stream);

    deg_h_kernel<<<K1_BLKS, 256, 0, stream>>>(eidx, x, W, deg, h);
    dinv_g_kernel<<<(NN + 255) / 256, 256, 0, stream>>>(deg, h, dinv, g);
    scatter_kernel<<<SC_BLKS, 256, 0, stream>>>(eidx, g, s);
    final_kernel<<<(NN + 255) / 256, 256, 0, stream>>>(s, g, dinv, b, out);
}

// Round 4
// 558.499 us; speedup vs baseline: 1.0281x; 1.0281x over previous
//
#include <hip/hip_runtime.h>
#include <math.h>

#define NN 100000
#define NNP 100352             // padded per-copy stride (401,408 B, 4 KB aligned)
#define NE 3200000
#define CF 512

// ---- ws layout (bytes) ----
// deg8 : u32[8][NNP] @ 0          (3,211,264)  per-XCD degree copies
// s8   : f32[8][NNP] @ 3,211,264  (3,211,264)  per-XCD scatter copies
// h    : f32[NN]     @ 6,422,528
// g    : f32[NN]     @ 6,823,936
// dinv : f32[NN]     @ 7,225,344
#define OFF_DEG8 0
#define OFF_S8   3211264
#define OFF_H    6422528
#define OFF_G    6823936
#define OFF_DINV 7225344
#define ZERO_BYTES 6422528      // deg8 + s8

// Physical XCD id of the executing CU [measured: learn_hip m09].
// Correctness of the per-XCD-copy scheme REQUIRES this to be the real XCD.
__device__ __forceinline__ unsigned xcc_id() {
    unsigned x;
    asm volatile("s_getreg_b32 %0, hwreg(HW_REG_XCC_ID)" : "=s"(x));
    return x & 7u;
}

// Workgroup-scope u32 atomic: no device-coherence flags -> RMW executes at the
// local XCD L2 (copy lines stay resident there), not memory-side.
__device__ __forceinline__ void atomic_add_u32_l2(unsigned* p, unsigned v) {
    __hip_atomic_fetch_add(p, v, __ATOMIC_RELAXED, __HIP_MEMORY_SCOPE_WORKGROUP);
}
// f32 variant via inline asm: guarantees native global_atomic_add_f32 with no
// sc0/sc1 (L2-executed), independent of -munsafe-fp-atomics codegen choices.
__device__ __forceinline__ void atomic_add_f32_l2(float* p, float v) {
    asm volatile("global_atomic_add_f32 %0, %1, off" :: "v"(p), "v"(v) : "memory");
}

// Per-wave int64-layout self-detect (high words of int64 edge values are 0).
__device__ __forceinline__ bool detect_f64(const int* e32) {
    unsigned v = ((const unsigned*)e32)[2 * (threadIdx.x & 63) + 1];
    return __ballot(v != 0u) == 0ULL;
}

__device__ __forceinline__ int4 load_col4(const int* e32, bool f64, int e) {
    if (f64) {
        const int4* q = (const int4*)(e32 + 2 * (NE + e));
        int4 a = q[0], b = q[1];
        return make_int4(a.x, a.z, b.x, b.z);
    }
    return *(const int4*)(e32 + NE + e);
}
__device__ __forceinline__ int4 load_row4(const int* e32, bool f64, int e) {
    if (f64) {
        const int4* q = (const int4*)(e32 + 2 * e);
        int4 a = q[0], b = q[1];
        return make_int4(a.x, a.z, b.x, b.z);
    }
    return *(const int4*)(e32 + e);
}

// ---------------------------------------------------------------------------
// K1 (block-specialized):
//   blocks [0,512)    : deg8[xcd][col]++ via XCD-local L2 atomics (edges read 1x)
//   blocks [512,2048) : h = x @ W^T (wave-per-node, 2-node ILP; x is L3-resident)
// 2048 blocks x 256 thr = exactly 8 blocks/CU, all co-resident.
// ---------------------------------------------------------------------------
#define EDGE_BLKS 512
#define H_BLKS    1536
#define K1_BLKS   (EDGE_BLKS + H_BLKS)

__global__ __launch_bounds__(256) void deg_h_kernel(const int* __restrict__ e32,
                                                    const float* __restrict__ x,
                                                    const float* __restrict__ W,
                                                    unsigned* __restrict__ deg8,
                                                    float* __restrict__ h) {
    int blk = blockIdx.x;
    if (blk < EDGE_BLKS) {
        unsigned* deg = deg8 + (size_t)xcc_id() * NNP;
        bool f64 = detect_f64(e32);
        int gid = blk * 256 + threadIdx.x;
        const int STRIDE = EDGE_BLKS * 256 * 4;   // 524288 edges per sweep
        for (int e = gid * 4; e < NE; e += STRIDE) {
            int4 c = load_col4(e32, f64, e);
            atomic_add_u32_l2(&deg[c.x], 1u);
            atomic_add_u32_l2(&deg[c.y], 1u);
            atomic_add_u32_l2(&deg[c.z], 1u);
            atomic_add_u32_l2(&deg[c.w], 1u);
        }
        asm volatile("s_waitcnt vmcnt(0)" ::: "memory");  // drain before endpgm
    } else {
        int wave = (blk - EDGE_BLKS) * 4 + (threadIdx.x >> 6);
        int lane = threadIdx.x & 63;
        const float4* Wr = (const float4*)W;
        float4 w0 = Wr[lane], w1 = Wr[lane + 64];   // W invariant, in regs
        const int NWAVES = H_BLKS * 4;              // 6144 waves
        for (int i = wave * 2; i < NN; i += NWAVES * 2) {
            int i1 = i + 1;
            float s0 = 0.f, s1 = 0.f;
            {
                const float4* xr = (const float4*)(x + (size_t)i * CF);
                float4 a = xr[lane], bq = xr[lane + 64];
                s0 = a.x * w0.x + a.y * w0.y + a.z * w0.z + a.w * w0.w
                   + bq.x * w1.x + bq.y * w1.y + bq.z * w1.z + bq.w * w1.w;
            }
            if (i1 < NN) {
                const float4* xr = (const float4*)(x + (size_t)i1 * CF);
                float4 a = xr[lane], bq = xr[lane + 64];
                s1 = a.x * w0.x + a.y * w0.y + a.z * w0.z + a.w * w0.w
                   + bq.x * w1.x + bq.y * w1.y + bq.z * w1.z + bq.w * w1.w;
            }
#pragma unroll
            for (int off = 32; off >= 1; off >>= 1) {
                s0 += __shfl_down(s0, off, 64);
                s1 += __shfl_down(s1, off, 64);
            }
            if (lane == 0) {
                h[i] = s0;
                if (i1 < NN) h[i1] = s1;
            }
        }
    }
}

// K2: d = 1 + sum_xcd deg8[.][i];  dinv = rsqrt(d);  g = h * dinv
__global__ __launch_bounds__(256) void dinv_g_kernel(const unsigned* __restrict__ deg8,
                                                     const float* __restrict__ h,
                                                     float* __restrict__ dinv,
                                                     float* __restrict__ g) {
    int i = blockIdx.x * 256 + threadIdx.x;
    if (i >= NN) return;
    unsigned d = 1;
#pragma unroll
    for (int k = 0; k < 8; ++k) d += deg8[(size_t)k * NNP + i];
    float di = rsqrtf((float)d);
    dinv[i] = di;
    g[i] = h[i] * di;
}

// K3: s8[xcd][col] += g[row] via XCD-local L2 f32 atomics (edges read 1x)
#define SC_BLKS 1024
__global__ __launch_bounds__(256) void scatter_kernel(const int* __restrict__ e32,
                                                      const float* __restrict__ g,
                                                      float* __restrict__ s8) {
    float* s = s8 + (size_t)xcc_id() * NNP;
    bool f64 = detect_f64(e32);
    int gid = blockIdx.x * 256 + threadIdx.x;
    const int STRIDE = SC_BLKS * 256 * 4;   // 1048576 edges per sweep
    for (int e = gid * 4; e < NE; e += STRIDE) {
        int4 c = load_col4(e32, f64, e);
        int4 r = load_row4(e32, f64, e);
        float g0 = g[r.x], g1 = g[r.y], g2 = g[r.z], g3 = g[r.w];
        atomic_add_f32_l2(&s[c.x], g0);
        atomic_add_f32_l2(&s[c.y], g1);
        atomic_add_f32_l2(&s[c.z], g2);
        atomic_add_f32_l2(&s[c.w], g3);
    }
    asm volatile("s_waitcnt vmcnt(0)" ::: "memory");  // drain asm atomics
}

// K4: out = sigmoid(dinv * (sum_xcd s8[.][i] + g) + b)
__global__ __launch_bounds__(256) void final_kernel(const float* __restrict__ s8,
                                                    const float* __restrict__ g,
                                                    const float* __restrict__ dinv,
                                                    const float* __restrict__ b,
                                                    float* __restrict__ out) {
    int i = blockIdx.x * 256 + threadIdx.x;
    if (i >= NN) return;
    float acc = g[i];
#pragma unroll
    for (int k = 0; k < 8; ++k) acc += s8[(size_t)k * NNP + i];
    float v = dinv[i] * acc + b[0];
    out[i] = 1.f / (1.f + expf(-v));
}

extern "C" void kernel_launch(void* const* d_in, const int* in_sizes, int n_in,
                              void* d_out, int out_size, void* d_ws, size_t ws_size,
                              hipStream_t stream) {
    const float* x = (const float*)d_in[0];
    const int* eidx = (const int*)d_in[1];
    const float* W = (const float*)d_in[2];
    const float* b = (const float*)d_in[3];
    float* out = (float*)d_out;

    char* ws = (char*)d_ws;
    unsigned* deg8 = (unsigned*)(ws + OFF_DEG8);
    float* s8 = (float*)(ws + OFF_S8);
    float* h = (float*)(ws + OFF_H);
    float* g = (float*)(ws + OFF_G);
    float* dinv = (float*)(ws + OFF_DINV);

    hipMemsetAsync(ws, 0, ZERO_BYTES, stream);   // zero deg8 + s8 (6.4 MB, ~1 us)

    deg_h_kernel<<<K1_BLKS, 256, 0, stream>>>(eidx, x, W, deg8, h);
    dinv_g_kernel<<<(NN + 255) / 256, 256, 0, stream>>>(deg8, h, dinv, g);
    scatter_kernel<<<SC_BLKS, 256, 0, stream>>>(eidx, g, s8);
    final_kernel<<<(NN + 255) / 256, 256, 0, stream>>>(s8, g, dinv, b, out);
}

// Round 5
// 376.288 us; speedup vs baseline: 1.5259x; 1.4842x over previous
//
#include <hip/hip_runtime.h>
#include <hip/hip_fp16.h>
#include <math.h>

#define NN 100000
#define NE 3200000
#define CF 512

// ---- ws layout (bytes) ----
// e32i  : int32 [2][NE] @ 0          (25,600,000)  converted edge index
// dpart : u16 partials  @ 25,600,000 (<= 25,600,000)  [NP*NSL][PT]
// spart : half partials @ 51,200,000 (12,800,000)     [NP*NSL][PT]
// h     : f32[NN]       @ 64,000,000
// g     : f32[NN]       @ 64,400,000
// dinv  : f32[NN]       @ 64,800,000
#define OFF_E32   0
#define OFF_DPART 25600000
#define OFF_SPART 51200000
#define OFF_H     64000000
#define OFF_G     64400000
#define OFF_DINV  64800000

// Per-wave int64-layout self-detect (high words of int64 edge values are 0).
__device__ __forceinline__ bool detect_f64(const int* e) {
    unsigned v = ((const unsigned*)e)[2 * (threadIdx.x & 63) + 1];
    return __ballot(v != 0u) == 0ULL;
}

// ---------------------------------------------------------------------------
// K0 (block-specialized): blocks [0,512) convert edge_index -> int32 [2][NE];
// blocks [512,2048) compute h = x @ W^T (wave-per-node, 2-node ILP).
// The 204.8 MB x-stream dominates; the convert hides under it.
// ---------------------------------------------------------------------------
#define CONV_BLKS 512
#define H_BLKS    1536

__global__ __launch_bounds__(256) void conv_h_kernel(const int* __restrict__ ein,
                                                     const float* __restrict__ x,
                                                     const float* __restrict__ W,
                                                     int* __restrict__ e32i,
                                                     float* __restrict__ h) {
    int blk = blockIdx.x;
    if (blk < CONV_BLKS) {
        bool f64 = detect_f64(ein);
        int gid = blk * 256 + threadIdx.x;
        const int TOT4 = (2 * NE) / 4;          // int4 output groups
        if (f64) {
            for (int j = gid; j < TOT4; j += CONV_BLKS * 256) {
                const int4* q = (const int4*)(ein + 8 * (size_t)j);  // 4 int64
                int4 a = q[0], b2 = q[1];
                *(int4*)(e32i + 4 * (size_t)j) = make_int4(a.x, a.z, b2.x, b2.z);
            }
        } else {
            for (int j = gid; j < TOT4; j += CONV_BLKS * 256) {
                *(int4*)(e32i + 4 * (size_t)j) = *(const int4*)(ein + 4 * (size_t)j);
            }
        }
    } else {
        int wave = (blk - CONV_BLKS) * 4 + (threadIdx.x >> 6);
        int lane = threadIdx.x & 63;
        const float4* Wr = (const float4*)W;
        float4 w0 = Wr[lane], w1 = Wr[lane + 64];   // W invariant, in regs
        const int NWAVES = H_BLKS * 4;
        for (int i = wave * 2; i < NN; i += NWAVES * 2) {
            int i1 = i + 1;
            float s0 = 0.f, s1 = 0.f;
            {
                const float4* xr = (const float4*)(x + (size_t)i * CF);
                float4 a = xr[lane], bq = xr[lane + 64];
                s0 = a.x * w0.x + a.y * w0.y + a.z * w0.z + a.w * w0.w
                   + bq.x * w1.x + bq.y * w1.y + bq.z * w1.z + bq.w * w1.w;
            }
            if (i1 < NN) {
                const float4* xr = (const float4*)(x + (size_t)i1 * CF);
                float4 a = xr[lane], bq = xr[lane + 64];
                s1 = a.x * w0.x + a.y * w0.y + a.z * w0.z + a.w * w0.w
                   + bq.x * w1.x + bq.y * w1.y + bq.z * w1.z + bq.w * w1.w;
            }
#pragma unroll
            for (int off = 32; off >= 1; off >>= 1) {
                s0 += __shfl_down(s0, off, 64);
                s1 += __shfl_down(s1, off, 64);
            }
            if (lane == 0) {
                h[i] = s0;
                if (i1 < NN) h[i1] = s1;
            }
        }
    }
}

// ---------------------------------------------------------------------------
// Deg histogram, LDS-privatized, u16-packed-in-u32 counters (max deg << 65535
// so low->high halfword carry is impossible). Grid = NP*NSL blocks; dynamic
// LDS = PT/2 u32 words. 16 edges/thread/iter for load MLP.
// ---------------------------------------------------------------------------
template<int NSL, int PT>
__global__ __launch_bounds__(1024) void deg_kernel(const int* __restrict__ e32i,
                                                   unsigned short* __restrict__ part) {
    extern __shared__ unsigned hist[];          // PT/2 packed pairs
    int tid = threadIdx.x;
    for (int i = tid; i < PT / 2; i += 1024) hist[i] = 0u;
    __syncthreads();
    const int EPB = NE / NSL;
    int p = blockIdx.x / NSL, s = blockIdx.x % NSL;
    unsigned lo = (unsigned)(p * PT);
    int base = s * EPB, lim = base + EPB;
    const int* ecol = e32i + NE;
    for (int e0 = base + tid * 4; e0 < lim; e0 += 16384) {
        int4 c[4];
#pragma unroll
        for (int k = 0; k < 4; ++k) {
            c[k] = make_int4((int)0x80000000, (int)0x80000000,
                             (int)0x80000000, (int)0x80000000);  // sentinel: never passes
            int e = e0 + k * 4096;
            if (e < lim) c[k] = *(const int4*)(ecol + e);
        }
#pragma unroll
        for (int k = 0; k < 4; ++k) {
            unsigned l0 = (unsigned)c[k].x - lo, l1 = (unsigned)c[k].y - lo;
            unsigned l2 = (unsigned)c[k].z - lo, l3 = (unsigned)c[k].w - lo;
            if (l0 < (unsigned)PT) atomicAdd(&hist[l0 >> 1], 1u << ((l0 & 1) << 4));
            if (l1 < (unsigned)PT) atomicAdd(&hist[l1 >> 1], 1u << ((l1 & 1) << 4));
            if (l2 < (unsigned)PT) atomicAdd(&hist[l2 >> 1], 1u << ((l2 & 1) << 4));
            if (l3 < (unsigned)PT) atomicAdd(&hist[l3 >> 1], 1u << ((l3 & 1) << 4));
        }
    }
    __syncthreads();
    unsigned short* outp = part + (size_t)blockIdx.x * PT;
    for (int i = tid; i < PT; i += 1024)
        outp[i] = (unsigned short)((hist[i >> 1] >> ((i & 1) << 4)) & 0xffffu);
}

// dinv[i] = rsqrt(1 + sum_slices dpart);  g[i] = h[i] * dinv[i]
template<int NSL, int PT>
__global__ __launch_bounds__(256) void dinv_g_kernel(const unsigned short* __restrict__ part,
                                                     const float* __restrict__ h,
                                                     float* __restrict__ dinv,
                                                     float* __restrict__ g) {
    int i = blockIdx.x * 256 + threadIdx.x;
    if (i >= NN) return;
    int p = i / PT, l = i - p * PT;
    const unsigned short* bp = part + ((size_t)p * NSL) * PT + l;
    unsigned d = 1;
#pragma unroll 16
    for (int s2 = 0; s2 < NSL; ++s2) d += bp[(size_t)s2 * PT];
    float di = rsqrtf((float)d);
    dinv[i] = di;
    g[i] = h[i] * di;
}

// ---------------------------------------------------------------------------
// Scatter s[col] += g[row], LDS-privatized f32, half partials out.
// Unconditional int4 row loads + unconditional g-gathers (sentinel rows -> g[0],
// harmless) give full 16-wide MLP with zero masked-load issue waste.
// ---------------------------------------------------------------------------
template<int NSL, int PT>
__global__ __launch_bounds__(1024) void scat_kernel(const int* __restrict__ e32i,
                                                    const float* __restrict__ g,
                                                    __half* __restrict__ part) {
    extern __shared__ float hs[];               // PT floats
    int tid = threadIdx.x;
    for (int i = tid; i < PT; i += 1024) hs[i] = 0.f;
    __syncthreads();
    const int EPB = NE / NSL;
    int p = blockIdx.x / NSL, s = blockIdx.x % NSL;
    unsigned lo = (unsigned)(p * PT);
    int base = s * EPB, lim = base + EPB;
    const int* ecol = e32i + NE;
    for (int e0 = base + tid * 4; e0 < lim; e0 += 16384) {
        int4 c[4], r[4];
#pragma unroll
        for (int k = 0; k < 4; ++k) {
            c[k] = make_int4((int)0x80000000, (int)0x80000000,
                             (int)0x80000000, (int)0x80000000);
            r[k] = make_int4(0, 0, 0, 0);
            int e = e0 + k * 4096;
            if (e < lim) {
                c[k] = *(const int4*)(ecol + e);
                r[k] = *(const int4*)(e32i + e);
            }
        }
        float gv[16];
#pragma unroll
        for (int k = 0; k < 4; ++k) {
            gv[4 * k + 0] = g[r[k].x];
            gv[4 * k + 1] = g[r[k].y];
            gv[4 * k + 2] = g[r[k].z];
            gv[4 * k + 3] = g[r[k].w];
        }
#pragma unroll
        for (int k = 0; k < 4; ++k) {
            unsigned l0 = (unsigned)c[k].x - lo, l1 = (unsigned)c[k].y - lo;
            unsigned l2 = (unsigned)c[k].z - lo, l3 = (unsigned)c[k].w - lo;
            if (l0 < (unsigned)PT) atomicAdd(&hs[l0], gv[4 * k + 0]);
            if (l1 < (unsigned)PT) atomicAdd(&hs[l1], gv[4 * k + 1]);
            if (l2 < (unsigned)PT) atomicAdd(&hs[l2], gv[4 * k + 2]);
            if (l3 < (unsigned)PT) atomicAdd(&hs[l3], gv[4 * k + 3]);
        }
    }
    __syncthreads();
    __half* outp = part + (size_t)blockIdx.x * PT;
    for (int i = tid; i < PT; i += 1024) outp[i] = __float2half(hs[i]);
}

// out[i] = sigmoid(dinv[i] * (sum_slices spart + g[i]) + b)
template<int NSL, int PT>
__global__ __launch_bounds__(256) void final_kernel(const __half* __restrict__ part,
                                                    const float* __restrict__ g,
                                                    const float* __restrict__ dinv,
                                                    const float* __restrict__ b,
                                                    float* __restrict__ out) {
    int i = blockIdx.x * 256 + threadIdx.x;
    if (i >= NN) return;
    int p = i / PT, l = i - p * PT;
    const __half* bp = part + ((size_t)p * NSL) * PT + l;
    float acc = g[i];
#pragma unroll 16
    for (int s2 = 0; s2 < NSL; ++s2) acc += __half2float(bp[(size_t)s2 * PT]);
    float v = dinv[i] * acc + b[0];
    out[i] = 1.f / (1.f + expf(-v));
}

extern "C" void kernel_launch(void* const* d_in, const int* in_sizes, int n_in,
                              void* d_out, int out_size, void* d_ws, size_t ws_size,
                              hipStream_t stream) {
    const float* x = (const float*)d_in[0];
    const int* eidx = (const int*)d_in[1];
    const float* W = (const float*)d_in[2];
    const float* b = (const float*)d_in[3];
    float* out = (float*)d_out;

    char* ws = (char*)d_ws;
    int* e32i = (int*)(ws + OFF_E32);
    unsigned short* dpart = (unsigned short*)(ws + OFF_DPART);
    __half* spart = (__half*)(ws + OFF_SPART);
    float* h = (float*)(ws + OFF_H);
    float* g = (float*)(ws + OFF_G);
    float* dinv = (float*)(ws + OFF_DINV);

    // One-time opt-in to >64KB dynamic LDS (gfx950 has 160KB/CU).
    static int bigOK = -1;
    if (bigOK < 0) {
        hipError_t a = hipFuncSetAttribute(
            reinterpret_cast<const void*>(&deg_kernel<128, 50000>),
            hipFuncAttributeMaxDynamicSharedMemorySize, 100000);
        hipError_t e = hipFuncSetAttribute(
            reinterpret_cast<const void*>(&scat_kernel<64, 25000>),
            hipFuncAttributeMaxDynamicSharedMemorySize, 100000);
        bigOK = (a == hipSuccess && e == hipSuccess) ? 1 : 0;
    }

    conv_h_kernel<<<CONV_BLKS + H_BLKS, 256, 0, stream>>>(eidx, x, W, e32i, h);

    if (bigOK) {
        // deg: NP=2 x NSL=128 = 256 blocks, 100KB LDS (PT=50000 packed u16)
        deg_kernel<128, 50000><<<256, 1024, 100000, stream>>>(e32i, dpart);
        dinv_g_kernel<128, 50000><<<(NN + 255) / 256, 256, 0, stream>>>(dpart, h, dinv, g);
        // scatter: NP=4 x NSL=64 = 256 blocks, 100KB LDS (PT=25000 f32)
        scat_kernel<64, 25000><<<256, 1024, 100000, stream>>>(e32i, g, spart);
        final_kernel<64, 25000><<<(NN + 255) / 256, 256, 0, stream>>>(spart, g, dinv, b, out);
    } else {
        // fallback (<=64KB dynamic LDS): deg NP=4/PT=25000 packed (50KB),
        // scatter NP=8/PT=12500 f32 (50KB)
        deg_kernel<64, 25000><<<256, 1024, 50000, stream>>>(e32i, dpart);
        dinv_g_kernel<64, 25000><<<(NN + 255) / 256, 256, 0, stream>>>(dpart, h, dinv, g);
        scat_kernel<64, 12500><<<512, 1024, 50000, stream>>>(e32i, g, spart);
        final_kernel<64, 12500><<<(NN + 255) / 256, 256, 0, stream>>>(spart, g, dinv, b, out);
    }
}